// Round 3
// baseline (40.199 us; speedup 1.0000x reference)
//
#include <hip/hip_runtime.h>

// Problem constants (reference: shape (32, 3, 512, 512) float32).
#define HW       (512 * 512)        // 262144 elements per channel plane
#define NPIX     (32 * HW)          // 8,388,608 pixels per tensor
#define NGROUP   (NPIX / 4)         // 2,097,152 float4 pixel-groups
#define NBLOCKS  4096
#define NTHREADS 256
#define TOTAL_T  (NBLOCKS * NTHREADS)   // 1,048,576 threads; 2 groups/thread

// s = (max-min)/max on rgb=(x+1)*0.5  ==  (mx-mn)/(mx+1) on raw x, 0 if mx+1==0
__device__ __forceinline__ float sat_raw(float r, float g, float b) {
    float mx = fmaxf(fmaxf(r, g), b);
    float mn = fminf(fminf(r, g), b);
    float vp = mx + 1.0f;
    return (vp > 0.0f) ? ((mx - mn) / vp) : 0.0f;
}

__device__ __forceinline__ float sat_diff4(
        const float4& ar, const float4& ag, const float4& ab,
        const float4& br, const float4& bg, const float4& bb) {
    float s = 0.0f;
    s += fabsf(sat_raw(ar.x, ag.x, ab.x) - sat_raw(br.x, bg.x, bb.x));
    s += fabsf(sat_raw(ar.y, ag.y, ab.y) - sat_raw(br.y, bg.y, bb.y));
    s += fabsf(sat_raw(ar.z, ag.z, ab.z) - sat_raw(br.z, bg.z, bb.z));
    s += fabsf(sat_raw(ar.w, ag.w, ab.w) - sat_raw(br.w, bg.w, bb.w));
    return s;
}

__global__ __launch_bounds__(NTHREADS, 8) void sat_loss_partial(
        const float* __restrict__ gen,
        const float* __restrict__ tgt,
        float* __restrict__ partial) {
    const unsigned tid = blockIdx.x * NTHREADS + threadIdx.x;   // 0 .. TOTAL_T-1

    // Two float4-groups per thread. 32-bit element offsets (max ~24.9M < 2^32/4).
    const unsigned g0 = tid;
    const unsigned g1 = tid + TOTAL_T;
    const unsigned off0 = (g0 >> 16) * (3u * HW) + ((g0 & 65535u) << 2);
    const unsigned off1 = (g1 >> 16) * (3u * HW) + ((g1 & 65535u) << 2);

    // Issue ALL 12 loads before any compute; sched_barrier(0) pins them here.
    const float4 a0r = *(const float4*)(gen + off0);
    const float4 a0g = *(const float4*)(gen + off0 + HW);
    const float4 a0b = *(const float4*)(gen + off0 + 2u * HW);
    const float4 b0r = *(const float4*)(tgt + off0);
    const float4 b0g = *(const float4*)(tgt + off0 + HW);
    const float4 b0b = *(const float4*)(tgt + off0 + 2u * HW);
    const float4 a1r = *(const float4*)(gen + off1);
    const float4 a1g = *(const float4*)(gen + off1 + HW);
    const float4 a1b = *(const float4*)(gen + off1 + 2u * HW);
    const float4 b1r = *(const float4*)(tgt + off1);
    const float4 b1g = *(const float4*)(tgt + off1 + HW);
    const float4 b1b = *(const float4*)(tgt + off1 + 2u * HW);

    __builtin_amdgcn_sched_barrier(0);   // no compute may be hoisted above, no load sunk below

    float acc = sat_diff4(a0r, a0g, a0b, b0r, b0g, b0b)
              + sat_diff4(a1r, a1g, a1b, b1r, b1g, b1b);

    // wave-64 reduce
    #pragma unroll
    for (int off = 32; off > 0; off >>= 1)
        acc += __shfl_down(acc, off, 64);

    __shared__ float wave_sum[NTHREADS / 64];
    const int lane = threadIdx.x & 63;
    const int wid  = threadIdx.x >> 6;
    if (lane == 0) wave_sum[wid] = acc;
    __syncthreads();

    if (threadIdx.x == 0) {
        float s = 0.0f;
        #pragma unroll
        for (int i = 0; i < NTHREADS / 64; ++i) s += wave_sum[i];
        partial[blockIdx.x] = s;
    }
}

__global__ __launch_bounds__(NTHREADS) void sat_loss_finalize(
        const float* __restrict__ partial,
        float* __restrict__ out) {
    float acc = 0.0f;
    for (int i = threadIdx.x; i < NBLOCKS; i += NTHREADS)
        acc += partial[i];

    #pragma unroll
    for (int off = 32; off > 0; off >>= 1)
        acc += __shfl_down(acc, off, 64);

    __shared__ float wave_sum[NTHREADS / 64];
    const int lane = threadIdx.x & 63;
    const int wid  = threadIdx.x >> 6;
    if (lane == 0) wave_sum[wid] = acc;
    __syncthreads();

    if (threadIdx.x == 0) {
        float s = 0.0f;
        #pragma unroll
        for (int i = 0; i < NTHREADS / 64; ++i) s += wave_sum[i];
        out[0] = s * (1.0f / (float)NPIX);   // WEIGHT == 1.0
    }
}

extern "C" void kernel_launch(void* const* d_in, const int* in_sizes, int n_in,
                              void* d_out, int out_size, void* d_ws, size_t ws_size,
                              hipStream_t stream) {
    const float* gen = (const float*)d_in[0];
    const float* tgt = (const float*)d_in[1];
    float* out = (float*)d_out;
    float* partial = (float*)d_ws;   // NBLOCKS floats = 16 KiB of scratch

    sat_loss_partial<<<NBLOCKS, NTHREADS, 0, stream>>>(gen, tgt, partial);
    sat_loss_finalize<<<1, NTHREADS, 0, stream>>>(partial, out);
}

// Round 4
// 39.854 us; speedup vs baseline: 1.0087x; 1.0087x over previous
//
#include <hip/hip_runtime.h>

// Problem constants (reference: shape (32, 3, 512, 512) float32).
#define HW       (512 * 512)        // 262144 elements per channel plane
#define NPIX     (32 * HW)          // 8,388,608 pixels per tensor
#define NGROUP   (NPIX / 4)         // 2,097,152 float4 pixel-groups
#define NBLOCKS  4096
#define NTHREADS 256
#define TOTAL_T  (NBLOCKS * NTHREADS)   // 1,048,576 threads; 2 groups/thread

// Byte strides for the inline-asm loads.
// channel plane stride = HW floats = 1 MiB; group1 delta = 16 batches = 48 MiB.
#define CH_B   0x100000u    // 1 MiB
#define G1_B   0x3000000u   // 48 MiB

typedef float f4 __attribute__((ext_vector_type(4)));

// s = (max-min)/max on rgb=(x+1)*0.5  ==  (mx-mn)/(mx+1) on raw x, 0 if mx+1==0
__device__ __forceinline__ float sat_raw(float r, float g, float b) {
    float mx = fmaxf(fmaxf(r, g), b);
    float mn = fminf(fminf(r, g), b);
    float vp = mx + 1.0f;
    return (vp > 0.0f) ? ((mx - mn) / vp) : 0.0f;
}

__device__ __forceinline__ float sat_diff4(
        const f4& ar, const f4& ag, const f4& ab,
        const f4& br, const f4& bg, const f4& bb) {
    float s = 0.0f;
    s += fabsf(sat_raw(ar.x, ag.x, ab.x) - sat_raw(br.x, bg.x, bb.x));
    s += fabsf(sat_raw(ar.y, ag.y, ab.y) - sat_raw(br.y, bg.y, bb.y));
    s += fabsf(sat_raw(ar.z, ag.z, ab.z) - sat_raw(br.z, bg.z, bb.z));
    s += fabsf(sat_raw(ar.w, ag.w, ab.w) - sat_raw(br.w, bg.w, bb.w));
    return s;
}

__global__ __launch_bounds__(NTHREADS, 8) void sat_loss_partial(
        const float* __restrict__ gen,
        const float* __restrict__ tgt,
        float* __restrict__ partial) {
    const unsigned tid = blockIdx.x * NTHREADS + threadIdx.x;   // 0 .. TOTAL_T-1

    // group0 byte offset; group1 = group0 + G1_B (constant delta, see header).
    const unsigned byte0 = ((tid >> 16) * (3u * HW) + ((tid & 65535u) << 2)) << 2;
    const unsigned vr0 = byte0;
    const unsigned vg0 = byte0 + CH_B;
    const unsigned vb0 = byte0 + 2u * CH_B;
    const unsigned vr1 = byte0 + G1_B;
    const unsigned vg1 = byte0 + G1_B + CH_B;
    const unsigned vb1 = byte0 + G1_B + 2u * CH_B;

    f4 a0r, a0g, a0b, b0r, b0g, b0b, a1r, a1g, a1b, b1r, b1g, b1b;
    // One atomic asm block: 12 loads back-to-back, then drain. 48 payload
    // VGPRs live simultaneously -> 12 KB per wave in flight.
    asm volatile(
        "global_load_dwordx4 %[o0],  %[p0], %[sg]\n\t"
        "global_load_dwordx4 %[o1],  %[p1], %[sg]\n\t"
        "global_load_dwordx4 %[o2],  %[p2], %[sg]\n\t"
        "global_load_dwordx4 %[o3],  %[p0], %[st]\n\t"
        "global_load_dwordx4 %[o4],  %[p1], %[st]\n\t"
        "global_load_dwordx4 %[o5],  %[p2], %[st]\n\t"
        "global_load_dwordx4 %[o6],  %[p3], %[sg]\n\t"
        "global_load_dwordx4 %[o7],  %[p4], %[sg]\n\t"
        "global_load_dwordx4 %[o8],  %[p5], %[sg]\n\t"
        "global_load_dwordx4 %[o9],  %[p3], %[st]\n\t"
        "global_load_dwordx4 %[o10], %[p4], %[st]\n\t"
        "global_load_dwordx4 %[o11], %[p5], %[st]\n\t"
        "s_waitcnt vmcnt(0)"
        : [o0]"=&v"(a0r), [o1]"=&v"(a0g), [o2]"=&v"(a0b),
          [o3]"=&v"(b0r), [o4]"=&v"(b0g), [o5]"=&v"(b0b),
          [o6]"=&v"(a1r), [o7]"=&v"(a1g), [o8]"=&v"(a1b),
          [o9]"=&v"(b1r), [o10]"=&v"(b1g), [o11]"=&v"(b1b)
        : [p0]"v"(vr0), [p1]"v"(vg0), [p2]"v"(vb0),
          [p3]"v"(vr1), [p4]"v"(vg1), [p5]"v"(vb1),
          [sg]"s"(gen), [st]"s"(tgt));

    float acc = sat_diff4(a0r, a0g, a0b, b0r, b0g, b0b)
              + sat_diff4(a1r, a1g, a1b, b1r, b1g, b1b);

    // wave-64 reduce
    #pragma unroll
    for (int off = 32; off > 0; off >>= 1)
        acc += __shfl_down(acc, off, 64);

    __shared__ float wave_sum[NTHREADS / 64];
    const int lane = threadIdx.x & 63;
    const int wid  = threadIdx.x >> 6;
    if (lane == 0) wave_sum[wid] = acc;
    __syncthreads();

    if (threadIdx.x == 0) {
        float s = 0.0f;
        #pragma unroll
        for (int i = 0; i < NTHREADS / 64; ++i) s += wave_sum[i];
        partial[blockIdx.x] = s;
    }
}

__global__ __launch_bounds__(NTHREADS) void sat_loss_finalize(
        const float* __restrict__ partial,
        float* __restrict__ out) {
    float acc = 0.0f;
    for (int i = threadIdx.x; i < NBLOCKS; i += NTHREADS)
        acc += partial[i];

    #pragma unroll
    for (int off = 32; off > 0; off >>= 1)
        acc += __shfl_down(acc, off, 64);

    __shared__ float wave_sum[NTHREADS / 64];
    const int lane = threadIdx.x & 63;
    const int wid  = threadIdx.x >> 6;
    if (lane == 0) wave_sum[wid] = acc;
    __syncthreads();

    if (threadIdx.x == 0) {
        float s = 0.0f;
        #pragma unroll
        for (int i = 0; i < NTHREADS / 64; ++i) s += wave_sum[i];
        out[0] = s * (1.0f / (float)NPIX);   // WEIGHT == 1.0
    }
}

extern "C" void kernel_launch(void* const* d_in, const int* in_sizes, int n_in,
                              void* d_out, int out_size, void* d_ws, size_t ws_size,
                              hipStream_t stream) {
    const float* gen = (const float*)d_in[0];
    const float* tgt = (const float*)d_in[1];
    float* out = (float*)d_out;
    float* partial = (float*)d_ws;   // NBLOCKS floats = 16 KiB of scratch

    sat_loss_partial<<<NBLOCKS, NTHREADS, 0, stream>>>(gen, tgt, partial);
    sat_loss_finalize<<<1, NTHREADS, 0, stream>>>(partial, out);
}